// Round 1
// baseline (1169.263 us; speedup 1.0000x reference)
//
#include <hip/hip_runtime.h>
#include <math.h>

// Problem constants (fixed by setup_inputs)
#define B_    2
#define N_    16384
#define M_    4096
#define CIN_  64
#define COUT_ 128
#define NC_   16            // n-chunks for kernel B grid (partials reduced in kernel C)
#define NCH_  (N_ / NC_)    // 1024 n per block

// g = -log(-log(u + eps) + eps)
// Inner log MUST be relative-accurate near u~1 (argmax winners live there): OCML logf.
// Outer log result is O(1..20): __logf (v_log_f32) absolute error ~1e-6 is fine.
__device__ __forceinline__ float gumbelf(float u) {
    float inner = logf(u + 1e-10f);
    float y = -inner + 1e-10f;
    return -__logf(y);
}

// ---------------------------------------------------------------------------
// Kernel A: fT[b][d][n] = relu( sum_c features[b][c][n] * W1[c][d] + b1[d] )
// Stored Cout-major so kernel B can stage f K-rows contiguously in n.
// ---------------------------------------------------------------------------
__global__ __launch_bounds__(256) void kA(const float* __restrict__ feat,
                                          const float* __restrict__ W1,
                                          const float* __restrict__ b1,
                                          float* __restrict__ fT) {
    __shared__ float sX[CIN_][64];     // [c][nn]
    __shared__ float sW1[CIN_][COUT_]; // [c][d]
    const int tid = threadIdx.x;
    const int b  = blockIdx.y;
    const int n0 = blockIdx.x * 64;

    #pragma unroll
    for (int i = 0; i < 16; ++i) {            // 64*64 floats
        int idx = tid + i * 256;
        int nn = idx & 63, c = idx >> 6;
        sX[c][nn] = feat[(b * CIN_ + c) * N_ + n0 + nn];
    }
    #pragma unroll
    for (int i = 0; i < 32; ++i) {            // 64*128 floats
        int idx = tid + i * 256;
        int d = idx & 127, c = idx >> 7;
        sW1[c][d] = W1[c * COUT_ + d];
    }
    __syncthreads();

    const int nn = tid & 63;
    const int dg = tid >> 6;                  // wave id: d block of 32
    float acc[32];
    #pragma unroll
    for (int j = 0; j < 32; ++j) acc[j] = 0.f;

    for (int c = 0; c < CIN_; ++c) {
        float x = sX[c][nn];
        const float4* wrow = (const float4*)&sW1[c][dg * 32];
        #pragma unroll
        for (int q = 0; q < 8; ++q) {
            float4 w4 = wrow[q];
            acc[q * 4 + 0] += x * w4.x;
            acc[q * 4 + 1] += x * w4.y;
            acc[q * 4 + 2] += x * w4.z;
            acc[q * 4 + 3] += x * w4.w;
        }
    }
    #pragma unroll
    for (int j = 0; j < 32; ++j) {
        int d = dg * 32 + j;
        float v = acc[j] + b1[d];
        v = v > 0.f ? v : 0.f;
        fT[(b * COUT_ + d) * N_ + n0 + nn] = v;
    }
}

// ---------------------------------------------------------------------------
// Kernel B: streaming GEMM + gumbel + argmax over n.
// Block: 64 m-cols x 1024 n-rows, 256 threads, 4x4 register tile.
// Writes per-(b, n-chunk) partial (max, argmax) per m.
// ---------------------------------------------------------------------------
__global__ __launch_bounds__(256) void kB(const float* __restrict__ fT,
                                          const float* __restrict__ W2,
                                          const float* __restrict__ b2,
                                          const float* __restrict__ u,
                                          float* __restrict__ pval,
                                          int* __restrict__ pidx) {
    __shared__ float sW2[COUT_][64];   // [k][mm] 32 KB, resident for whole block
    __shared__ float sF[COUT_][64];    // [k][nn] 32 KB, per 64-n subtile
    const int tid   = threadIdx.x;
    const int b     = blockIdx.z;
    const int m0    = blockIdx.x * 64;
    const int nbase = blockIdx.y * NCH_;

    #pragma unroll
    for (int i = 0; i < 8; ++i) {             // 128x64 floats as float4
        int idx = tid + i * 256;
        int mq = idx & 15, k = idx >> 4;
        *(float4*)&sW2[k][mq * 4] = *(const float4*)&W2[k * M_ + m0 + mq * 4];
    }

    const int tm = tid & 15;                  // m group (4 m each)
    const int tn = tid >> 4;                  // n group (4 n each)
    const float4 b2v = *(const float4*)&b2[m0 + tm * 4];

    float bestv[4];
    int   besti[4];
    #pragma unroll
    for (int j = 0; j < 4; ++j) { bestv[j] = -INFINITY; besti[j] = 0; }

    for (int s = 0; s < NCH_ / 64; ++s) {     // 16 subtiles of 64 n
        const int nb = nbase + s * 64;
        __syncthreads();                      // prev readers of sF done (also covers sW2 at s=0)
        #pragma unroll
        for (int i = 0; i < 8; ++i) {
            int idx = tid + i * 256;
            int nq = idx & 15, k = idx >> 4;
            *(float4*)&sF[k][nq * 4] = *(const float4*)&fT[(b * COUT_ + k) * N_ + nb + nq * 4];
        }
        __syncthreads();

        float acc[4][4];
        #pragma unroll
        for (int i = 0; i < 4; ++i)
            #pragma unroll
            for (int j = 0; j < 4; ++j) acc[i][j] = 0.f;

        #pragma unroll 16
        for (int k = 0; k < COUT_; ++k) {
            float4 a = *(const float4*)&sF[k][tn * 4];
            float4 w = *(const float4*)&sW2[k][tm * 4];
            acc[0][0] += a.x * w.x; acc[0][1] += a.x * w.y; acc[0][2] += a.x * w.z; acc[0][3] += a.x * w.w;
            acc[1][0] += a.y * w.x; acc[1][1] += a.y * w.y; acc[1][2] += a.y * w.z; acc[1][3] += a.y * w.w;
            acc[2][0] += a.z * w.x; acc[2][1] += a.z * w.y; acc[2][2] += a.z * w.z; acc[2][3] += a.z * w.w;
            acc[3][0] += a.w * w.x; acc[3][1] += a.w * w.y; acc[3][2] += a.w * w.z; acc[3][3] += a.w * w.w;
        }

        #pragma unroll
        for (int i = 0; i < 4; ++i) {
            const int n = nb + tn * 4 + i;
            float4 u4 = *(const float4*)&u[(b * N_ + n) * M_ + m0 + tm * 4];
            float g0 = gumbelf(u4.x), g1 = gumbelf(u4.y), g2 = gumbelf(u4.z), g3 = gumbelf(u4.w);
            float v0 = acc[i][0] + b2v.x + g0;
            float v1 = acc[i][1] + b2v.y + g1;
            float v2 = acc[i][2] + b2v.z + g2;
            float v3 = acc[i][3] + b2v.w + g3;
            // n strictly increases within a thread: strict > keeps first occurrence
            if (v0 > bestv[0]) { bestv[0] = v0; besti[0] = n; }
            if (v1 > bestv[1]) { bestv[1] = v1; besti[1] = n; }
            if (v2 > bestv[2]) { bestv[2] = v2; besti[2] = n; }
            if (v3 > bestv[3]) { bestv[3] = v3; besti[3] = n; }
        }
    }

    // Reduce across tn. In-wave: lanes sharing (lane&15) differ in n-group -> xor 16, 32.
    #pragma unroll
    for (int j = 0; j < 4; ++j) {
        #pragma unroll
        for (int off = 16; off <= 32; off <<= 1) {
            float ov = __shfl_xor(bestv[j], off, 64);
            int   oi = __shfl_xor(besti[j], off, 64);
            if (ov > bestv[j] || (ov == bestv[j] && oi < besti[j])) { bestv[j] = ov; besti[j] = oi; }
        }
    }
    __syncthreads();                          // done reading sF; reuse as reduce scratch
    float* redv = &sF[0][0];                  // 4 waves x 64 m
    int*   redi = (int*)&sF[16][0];
    const int wave = tid >> 6, lane = tid & 63;
    if (lane < 16) {
        #pragma unroll
        for (int j = 0; j < 4; ++j) {
            redv[wave * 64 + lane * 4 + j] = bestv[j];
            redi[wave * 64 + lane * 4 + j] = besti[j];
        }
    }
    __syncthreads();
    if (tid < 64) {
        float v = redv[tid];
        int  ii = redi[tid];
        #pragma unroll
        for (int w = 1; w < 4; ++w) {
            float ov = redv[w * 64 + tid];
            int   oi = redi[w * 64 + tid];
            if (ov > v || (ov == v && oi < ii)) { v = ov; ii = oi; }
        }
        int off = (b * NC_ + blockIdx.y) * M_ + m0 + tid;
        pval[off] = v;
        pidx[off] = ii;
    }
}

// ---------------------------------------------------------------------------
// Kernel C: reduce n-chunk partials, gather xyz/feat, write indices (as f32).
// ---------------------------------------------------------------------------
__global__ __launch_bounds__(256) void kC(const float* __restrict__ pval,
                                          const int* __restrict__ pidx,
                                          const float* __restrict__ xyzs,
                                          const float* __restrict__ fT,
                                          float* __restrict__ out) {
    const int t = blockIdx.x * 256 + threadIdx.x;   // 0 .. B*M-1
    const int b = t >> 12;
    const int m = t & (M_ - 1);

    float bv = -INFINITY;
    int   bi = 0;
    #pragma unroll
    for (int nc = 0; nc < NC_; ++nc) {              // chunks in increasing-n order
        int off = (b * NC_ + nc) * M_ + m;
        float v = pval[off];
        int  ii = pidx[off];
        if (v > bv || (v == bv && ii < bi)) { bv = v; bi = ii; }
    }

    // xyz_out: (B, M, 3)
    #pragma unroll
    for (int c = 0; c < 3; ++c)
        out[(b * M_ + m) * 3 + c] = xyzs[(b * N_ + bi) * 3 + c];

    // feat_out: (B, COUT, M) at offset B*M*3  (coalesced writes over m)
    float* featp = out + B_ * M_ * 3;
    for (int d = 0; d < COUT_; ++d)
        featp[(b * COUT_ + d) * M_ + m] = fT[(b * COUT_ + d) * N_ + bi];

    // indices: (B, M) as float, after feat_out
    out[B_ * M_ * 3 + B_ * COUT_ * M_ + b * M_ + m] = (float)bi;
}

extern "C" void kernel_launch(void* const* d_in, const int* in_sizes, int n_in,
                              void* d_out, int out_size, void* d_ws, size_t ws_size,
                              hipStream_t stream) {
    const float* xyzs = (const float*)d_in[0];
    const float* feat = (const float*)d_in[1];
    const float* u    = (const float*)d_in[2];
    const float* W1   = (const float*)d_in[3];
    const float* b1   = (const float*)d_in[4];
    const float* W2   = (const float*)d_in[5];
    const float* b2   = (const float*)d_in[6];
    float* out = (float*)d_out;

    char* ws = (char*)d_ws;
    float* fT   = (float*)ws;                                          // B*COUT*N f32 = 16 MB
    float* pval = (float*)(ws + (size_t)B_ * COUT_ * N_ * 4);          // B*NC*M f32
    int*   pidx = (int*)  (ws + (size_t)B_ * COUT_ * N_ * 4
                              + (size_t)B_ * NC_ * M_ * 4);            // B*NC*M i32

    kA<<<dim3(N_ / 64, B_), 256, 0, stream>>>(feat, W1, b1, fT);
    kB<<<dim3(M_ / 64, NC_, B_), 256, 0, stream>>>(fT, W2, b2, u, pval, pidx);
    kC<<<dim3(B_ * M_ / 256), 256, 0, stream>>>(pval, pidx, xyzs, fT, out);
}

// Round 2
// 903.182 us; speedup vs baseline: 1.2946x; 1.2946x over previous
//
#include <hip/hip_runtime.h>
#include <math.h>

#define B_    2
#define N_    16384
#define M_    4096
#define CIN_  64
#define COUT_ 128
#define NCB_  64            // n-chunks (256 n each) for kB partials

typedef _Float16 half8 __attribute__((ext_vector_type(8)));
typedef float    f32x4 __attribute__((ext_vector_type(4)));

#define LO_SCALE 4096.0f
#define LO_INV   (1.0f/4096.0f)

// g = -log(-log(u + eps) + eps)
// Inner log needs full RELATIVE accuracy near u~1 (argmax winners live there): OCML logf.
// Outer log result is O(1..20): __logf absolute error ~1e-6 is fine.
__device__ __forceinline__ float gumbelf(float u) {
    float inner = logf(u + 1e-10f);
    float y = -inner + 1e-10f;
    return -__logf(y);
}

// ---------------------------------------------------------------------------
// kW: split W2 (K x M, k-major) into f16 hi/lo, transposed m-major:
// w2h[m][k], w2l[m][k] (lo pre-scaled by 2^12). 128*4096 elements.
// ---------------------------------------------------------------------------
__global__ __launch_bounds__(256) void kW(const float* __restrict__ W2,
                                          _Float16* __restrict__ w2h,
                                          _Float16* __restrict__ w2l) {
    const int t = blockIdx.x * 256 + threadIdx.x;  // 65536 threads
    const int m = t >> 4, q = t & 15;              // q: 8-k chunk
    half8 hv, lv;
    #pragma unroll
    for (int j = 0; j < 8; ++j) {
        float v = W2[(q * 8 + j) * M_ + m];
        _Float16 h = (_Float16)v;
        hv[j] = h;
        lv[j] = (_Float16)((v - (float)h) * LO_SCALE);
    }
    *(half8*)&w2h[m * COUT_ + q * 8] = hv;
    *(half8*)&w2l[m * COUT_ + q * 8] = lv;
}

// ---------------------------------------------------------------------------
// kA: f[n][d] = relu(feat^T @ W1 + b1), written as f16 hi/lo in k-chunk-major
// layout: fhiC[b][kc][n][32] (kc = d>>5), lo pre-scaled by 2^12.
// ---------------------------------------------------------------------------
__global__ __launch_bounds__(256) void kA(const float* __restrict__ feat,
                                          const float* __restrict__ W1,
                                          const float* __restrict__ b1,
                                          _Float16* __restrict__ fhiC,
                                          _Float16* __restrict__ floC) {
    __shared__ float sX[CIN_][64];
    __shared__ float sW1[CIN_][COUT_];
    const int tid = threadIdx.x;
    const int b  = blockIdx.y;
    const int n0 = blockIdx.x * 64;

    #pragma unroll
    for (int i = 0; i < 16; ++i) {
        int idx = tid + i * 256;
        int nn = idx & 63, cc = idx >> 6;
        sX[cc][nn] = feat[(b * CIN_ + cc) * N_ + n0 + nn];
    }
    #pragma unroll
    for (int i = 0; i < 32; ++i) {
        int idx = tid + i * 256;
        int d = idx & 127, cc = idx >> 7;
        sW1[cc][d] = W1[cc * COUT_ + d];
    }
    __syncthreads();

    const int nn = tid & 63;
    const int dg = tid >> 6;               // d-chunk 0..3 == kc
    float acc[32];
    #pragma unroll
    for (int j = 0; j < 32; ++j) acc[j] = 0.f;

    for (int cc = 0; cc < CIN_; ++cc) {
        float x = sX[cc][nn];
        const float4* wrow = (const float4*)&sW1[cc][dg * 32];
        #pragma unroll
        for (int qq = 0; qq < 8; ++qq) {
            float4 w4 = wrow[qq];
            acc[qq * 4 + 0] += x * w4.x;
            acc[qq * 4 + 1] += x * w4.y;
            acc[qq * 4 + 2] += x * w4.z;
            acc[qq * 4 + 3] += x * w4.w;
        }
    }

    const size_t base = ((size_t)(b * 4 + dg) * N_ + n0 + nn) * 32;
    #pragma unroll
    for (int g = 0; g < 4; ++g) {
        half8 hv, lv;
        #pragma unroll
        for (int j = 0; j < 8; ++j) {
            int jj = g * 8 + j;
            float v = acc[jj] + b1[dg * 32 + jj];
            v = v > 0.f ? v : 0.f;
            _Float16 h = (_Float16)v;
            hv[j] = h;
            lv[j] = (_Float16)((v - (float)h) * LO_SCALE);
        }
        *(half8*)&fhiC[base + g * 8] = hv;
        *(half8*)&floC[base + g * 8] = lv;
    }
}

// ---------------------------------------------------------------------------
// kB: MFMA split-f16 GEMM (w = f @ W2, no b2 -- constant per column, argmax-
// invariant) + gumbel + argmax over n. Block: 128 m x 256 n, 4 waves; each
// wave 32 m x 64 n per subblock, 4 subblocks. B-frags direct from global
// (coalesced 1KB/wave, L1-reused). 3 MFMAs per k-chunk per tile:
// acc1 += Ah*Bh;  acc2 += Ah*Bl' + Al'*Bh  (lo' = lo*2^12).
// ---------------------------------------------------------------------------
__global__ __launch_bounds__(256, 2) void kB(const _Float16* __restrict__ fhiC,
                                             const _Float16* __restrict__ floC,
                                             const _Float16* __restrict__ w2h,
                                             const _Float16* __restrict__ w2l,
                                             const float* __restrict__ u,
                                             float* __restrict__ pval,
                                             int* __restrict__ pidx) {
    const int tid  = threadIdx.x;
    const int wv   = tid >> 6;
    const int lane = tid & 63;
    const int c    = lane & 15;            // n-index within tile / m-index of A-frag
    const int q    = lane >> 4;            // k-octet
    const int b    = blockIdx.z;
    const int m0   = blockIdx.x * 128 + wv * 32;
    const int nblk = blockIdx.y * 256;

    // A-frags (W2^T strips), resident: lane holds A[m=c][k=q*8+j]
    half8 Ah[2][4], Al[2][4];
    #pragma unroll
    for (int mt = 0; mt < 2; ++mt)
        #pragma unroll
        for (int kc = 0; kc < 4; ++kc) {
            const int aoff = (m0 + mt * 16 + c) * COUT_ + kc * 32 + q * 8;
            Ah[mt][kc] = *(const half8*)&w2h[aoff];
            Al[mt][kc] = *(const half8*)&w2l[aoff];
        }

    float bestv[2][4];
    int   besti[2][4];
    #pragma unroll
    for (int mt = 0; mt < 2; ++mt)
        #pragma unroll
        for (int r = 0; r < 4; ++r) { bestv[mt][r] = -INFINITY; besti[mt][r] = 0; }

    for (int ns = 0; ns < 4; ++ns) {
        const int nbase = nblk + ns * 64;
        f32x4 acc1[2][4], acc2[2][4];
        #pragma unroll
        for (int mt = 0; mt < 2; ++mt)
            #pragma unroll
            for (int nt = 0; nt < 4; ++nt) {
                acc1[mt][nt] = (f32x4)0.f;
                acc2[mt][nt] = (f32x4)0.f;
            }

        #pragma unroll
        for (int kc = 0; kc < 4; ++kc) {
            const size_t fb = ((size_t)(b * 4 + kc) * N_ + nbase) * 32;
            #pragma unroll
            for (int nt = 0; nt < 4; ++nt) {
                const size_t off = fb + (size_t)(nt * 16 + c) * 32 + q * 8;
                half8 Bh = *(const half8*)&fhiC[off];
                half8 Bl = *(const half8*)&floC[off];
                #pragma unroll
                for (int mt = 0; mt < 2; ++mt) {
                    acc1[mt][nt] = __builtin_amdgcn_mfma_f32_16x16x32_f16(Ah[mt][kc], Bh, acc1[mt][nt], 0, 0, 0);
                    acc2[mt][nt] = __builtin_amdgcn_mfma_f32_16x16x32_f16(Ah[mt][kc], Bl, acc2[mt][nt], 0, 0, 0);
                    acc2[mt][nt] = __builtin_amdgcn_mfma_f32_16x16x32_f16(Al[mt][kc], Bh, acc2[mt][nt], 0, 0, 0);
                }
            }
        }

        // epilogue: D row(m) = q*4+reg, col(n) = c
        #pragma unroll
        for (int nt = 0; nt < 4; ++nt) {
            const int n = nbase + nt * 16 + c;
            #pragma unroll
            for (int mt = 0; mt < 2; ++mt) {
                const int mb = m0 + mt * 16 + q * 4;
                const float4 u4 = *(const float4*)&u[((size_t)b * N_ + n) * M_ + mb];
                float uu[4] = {u4.x, u4.y, u4.z, u4.w};
                #pragma unroll
                for (int r = 0; r < 4; ++r) {
                    float v = acc1[mt][nt][r] + acc2[mt][nt][r] * LO_INV + gumbelf(uu[r]);
                    // n strictly increases per lane: strict > keeps first occurrence
                    if (v > bestv[mt][r]) { bestv[mt][r] = v; besti[mt][r] = n; }
                }
            }
        }
    }

    // reduce across the 16 n-lanes (c): butterfly xor 1,2,4,8 with min-index tie-break
    #pragma unroll
    for (int mt = 0; mt < 2; ++mt)
        #pragma unroll
        for (int r = 0; r < 4; ++r) {
            float v = bestv[mt][r];
            int   i = besti[mt][r];
            #pragma unroll
            for (int off = 1; off <= 8; off <<= 1) {
                float ov = __shfl_xor(v, off, 64);
                int   oi = __shfl_xor(i, off, 64);
                if (ov > v || (ov == v && oi < i)) { v = ov; i = oi; }
            }
            bestv[mt][r] = v; besti[mt][r] = i;
        }

    if (c == 0) {
        #pragma unroll
        for (int mt = 0; mt < 2; ++mt)
            #pragma unroll
            for (int r = 0; r < 4; ++r) {
                int off = (b * NCB_ + blockIdx.y) * M_ + m0 + mt * 16 + q * 4 + r;
                pval[off] = bestv[mt][r];
                pidx[off] = besti[mt][r];
            }
    }
}

// ---------------------------------------------------------------------------
// kC: reduce 64 n-chunk partials per (b,m), gather xyz, cooperative feat
// gather with LDS transpose, write indices as f32.
// ---------------------------------------------------------------------------
__global__ __launch_bounds__(256) void kC(const float* __restrict__ pval,
                                          const int* __restrict__ pidx,
                                          const float* __restrict__ xyzs,
                                          const _Float16* __restrict__ fhiC,
                                          const _Float16* __restrict__ floC,
                                          float* __restrict__ out) {
    __shared__ float rv[4][64];
    __shared__ int   ri[4][64];
    __shared__ int   sbi[64];
    __shared__ float sT[128][65];   // [d][m], padded
    const int tid = threadIdx.x;
    const int b   = blockIdx.y;
    const int m0  = blockIdx.x * 64;

    // phase 1: reduce partials (64 chunks, 4 groups of 16)
    {
        const int cg = tid >> 6, ml = tid & 63;
        float bv = -INFINITY;
        int   bi = 0;
        for (int i = 0; i < 16; ++i) {
            int nc = cg * 16 + i;
            int off = (b * NCB_ + nc) * M_ + m0 + ml;
            float v = pval[off];
            int  ii = pidx[off];
            if (v > bv || (v == bv && ii < bi)) { bv = v; bi = ii; }
        }
        rv[cg][ml] = bv; ri[cg][ml] = bi;
    }
    __syncthreads();
    if (tid < 64) {
        float bv = rv[0][tid];
        int   bi = ri[0][tid];
        #pragma unroll
        for (int w = 1; w < 4; ++w) {
            float ov = rv[w][tid];
            int   oi = ri[w][tid];
            if (ov > bv || (ov == bv && oi < bi)) { bv = ov; bi = oi; }
        }
        sbi[tid] = bi;
        const int m = m0 + tid;
        #pragma unroll
        for (int c3 = 0; c3 < 3; ++c3)
            out[((size_t)b * M_ + m) * 3 + c3] = xyzs[((size_t)b * N_ + bi) * 3 + c3];
        out[(size_t)B_ * M_ * 3 + (size_t)B_ * COUT_ * M_ + b * M_ + m] = (float)bi;
    }
    __syncthreads();

    // phase 2: gather f rows (reconstruct fp32 = hi + lo/2^12) into LDS tile
    {
        const int d = tid & 127, mg = tid >> 7;
        for (int it = 0; it < 32; ++it) {
            int ml = it * 2 + mg;
            int bi2 = sbi[ml];
            int kc = d >> 5, j = d & 31;
            size_t off = ((size_t)(b * 4 + kc) * N_ + bi2) * 32 + j;
            sT[d][ml] = (float)fhiC[off] + (float)floC[off] * LO_INV;
        }
    }
    __syncthreads();
    // phase 3: coalesced writes over m
    {
        float* featp = out + (size_t)B_ * M_ * 3;
        const int dg = tid >> 6, ml = tid & 63;
        for (int it = 0; it < 32; ++it) {
            int dd = it * 4 + dg;
            featp[((size_t)b * COUT_ + dd) * M_ + m0 + ml] = sT[dd][ml];
        }
    }
}

extern "C" void kernel_launch(void* const* d_in, const int* in_sizes, int n_in,
                              void* d_out, int out_size, void* d_ws, size_t ws_size,
                              hipStream_t stream) {
    const float* xyzs = (const float*)d_in[0];
    const float* feat = (const float*)d_in[1];
    const float* u    = (const float*)d_in[2];
    const float* W1   = (const float*)d_in[3];
    const float* b1   = (const float*)d_in[4];
    const float* W2   = (const float*)d_in[5];
    // b2 (d_in[6]) is provably unused: constant over n, cancels in argmax,
    // and w never reaches any output.
    float* out = (float*)d_out;

    _Float16* fhiC = (_Float16*)d_ws;                       // 2*4*16384*32 = 8 MB
    _Float16* floC = fhiC + (size_t)B_ * 4 * N_ * 32;       // 8 MB
    _Float16* w2h  = floC + (size_t)B_ * 4 * N_ * 32;       // 1 MB
    _Float16* w2l  = w2h + (size_t)M_ * COUT_;              // 1 MB
    float*    pval = (float*)(w2l + (size_t)M_ * COUT_);    // 2 MB
    int*      pidx = (int*)(pval + (size_t)B_ * NCB_ * M_); // 2 MB

    kW<<<dim3(M_ * 16 / 256), 256, 0, stream>>>(W2, w2h, w2l);
    kA<<<dim3(N_ / 64, B_), 256, 0, stream>>>(feat, W1, b1, fhiC, floC);
    kB<<<dim3(M_ / 128, NCB_, B_), 256, 0, stream>>>(fhiC, floC, w2h, w2l, u, pval, pidx);
    kC<<<dim3(M_ / 64, B_), 256, 0, stream>>>(pval, pidx, xyzs, fhiC, floC, out);
}